// Round 1
// baseline (181.192 us; speedup 1.0000x reference)
//
#include <hip/hip_runtime.h>
#include <hip/hip_bf16.h>

#define Bsz 256
#define Tn 2048
#define QD 1024
#define AD 128
#define DCn 8
#define DKn 21
#define PLn 11
#define GN (DCn * DKn)   // 168

// ---------------------------------------------------------------------------
// Kernel 1: per-sample dynamic filters
//   h = tanh(query @ W_w^T + W_b)        (B,128)
//   G = h @ V_w^T                        (B,168) -> d_ws
// One 256-thread block per b. Coalesced float4 loads, wave shuffle reduce.
// ---------------------------------------------------------------------------
__global__ __launch_bounds__(256) void g_kernel(
    const float* __restrict__ query, const float* __restrict__ W_w,
    const float* __restrict__ W_b, const float* __restrict__ V_w,
    float* __restrict__ G_ws)
{
    __shared__ float h_lds[AD];
    const int b    = blockIdx.x;
    const int tid  = threadIdx.x;
    const int w    = tid >> 6;
    const int lane = tid & 63;

    // hoist the query row into registers: 4 float4 per lane covers 1024 floats/wave
    const float4* q4 = (const float4*)(query + b * QD);
    float4 q0 = q4[lane];
    float4 q1 = q4[64 + lane];
    float4 q2 = q4[128 + lane];
    float4 q3 = q4[192 + lane];

    // each wave handles 32 of the 128 hidden units
    for (int i = 0; i < 32; ++i) {
        int a = w * 32 + i;
        const float4* w4 = (const float4*)(W_w + a * QD);
        float acc = 0.f;
        float4 x;
        x = w4[lane];
        acc = fmaf(q0.x, x.x, fmaf(q0.y, x.y, fmaf(q0.z, x.z, fmaf(q0.w, x.w, acc))));
        x = w4[64 + lane];
        acc = fmaf(q1.x, x.x, fmaf(q1.y, x.y, fmaf(q1.z, x.z, fmaf(q1.w, x.w, acc))));
        x = w4[128 + lane];
        acc = fmaf(q2.x, x.x, fmaf(q2.y, x.y, fmaf(q2.z, x.z, fmaf(q2.w, x.w, acc))));
        x = w4[192 + lane];
        acc = fmaf(q3.x, x.x, fmaf(q3.y, x.y, fmaf(q3.z, x.z, fmaf(q3.w, x.w, acc))));
        #pragma unroll
        for (int off = 32; off; off >>= 1) acc += __shfl_xor(acc, off);
        if (lane == 0) h_lds[a] = tanhf(acc + W_b[a]);
    }
    __syncthreads();

    // G[b, r] = sum_a h[a] * V_w[r*128 + a], r in [0,168)
    for (int r = w; r < GN; r += 4) {
        float acc = fmaf(h_lds[lane], V_w[r * AD + lane],
                         h_lds[64 + lane] * V_w[r * AD + 64 + lane]);
        #pragma unroll
        for (int off = 32; off; off >>= 1) acc += __shfl_xor(acc, off);
        if (lane == 0) G_ws[b * GN + r] = acc;
    }
}

// ---------------------------------------------------------------------------
// Kernel 2: fused windows -> prior/f/g -> tanh MLP -> e -> row softmax.
// One 1024-thread block per b; each thread owns t = tid and t = tid+1024.
// All weights read at wave-uniform indices (scalar-load path); alignment row
// staged in LDS for the per-lane 21-tap windows.
// ---------------------------------------------------------------------------
__global__ __launch_bounds__(1024) void e_kernel(
    const float* __restrict__ align, const float* __restrict__ P,
    const float* __restrict__ F_w, const float* __restrict__ U_w,
    const float* __restrict__ T_w, const float* __restrict__ T_b,
    const float* __restrict__ v_w, const float* __restrict__ G_ws,
    float* __restrict__ out)
{
    __shared__ float al[Tn + 20];
    __shared__ float red[16];
    __shared__ float bc[2];

    const int b    = blockIdx.x;
    const int tid  = threadIdx.x;
    const int lane = tid & 63;
    const int wid  = tid >> 6;

    // stage padded alignment row (pad = 10 zeros each side)
    for (int i = tid; i < Tn + 20; i += 1024) {
        int s = i - 10;
        al[i] = (s >= 0 && s < Tn) ? align[b * Tn + s] : 0.f;
    }
    __syncthreads();

    const float* Gp = G_ws + b * GN;

    float fA[2][8], gA[2][8], pA[2];
    #pragma unroll
    for (int tt = 0; tt < 2; ++tt) {
        const int t = tid + tt * 1024;
        float w[DKn];
        #pragma unroll
        for (int k = 0; k < DKn; ++k) w[k] = al[t + k];

        // prior: first 11 taps against (already flipped) P, then log(clip(.))
        float pr = 0.f;
        #pragma unroll
        for (int k = 0; k < PLn; ++k) pr = fmaf(w[k], P[k], pr);
        pA[tt] = __logf(fmaxf(pr, 1e-6f));

        // static conv f and dynamic conv g (weights at uniform indices)
        #pragma unroll
        for (int c = 0; c < DCn; ++c) {
            float fa = 0.f, ga = 0.f;
            #pragma unroll
            for (int k = 0; k < DKn; ++k) {
                fa = fmaf(w[k], F_w[c * DKn + k], fa);
                ga = fmaf(w[k], Gp[c * DKn + k], ga);
            }
            fA[tt][c] = fa;
            gA[tt][c] = ga;
        }
    }

    // e_inner[t] = sum_a v[a] * tanh( U[a,:].f + T[a,:].g + tb[a] )
    float ea0 = 0.f, ea1 = 0.f;
    #pragma unroll 2
    for (int a = 0; a < AD; ++a) {
        float tb = T_b[a];
        float vv = v_w[a];
        float u0 = tb, u1 = tb, s0 = 0.f, s1 = 0.f;
        #pragma unroll
        for (int c = 0; c < DCn; ++c) {
            float uw = U_w[a * DCn + c];
            float tw = T_w[a * DCn + c];
            u0 = fmaf(uw, fA[0][c], u0);
            u1 = fmaf(uw, fA[1][c], u1);
            s0 = fmaf(tw, gA[0][c], s0);
            s1 = fmaf(tw, gA[1][c], s1);
        }
        float x0 = u0 + s0, x1 = u1 + s1;
        // tanh(x) = 1 - 2/(exp(2x)+1); saturates correctly at +/-inf
        float q0 = __expf(2.f * x0);
        float q1 = __expf(2.f * x1);
        float r0 = __builtin_amdgcn_rcpf(q0 + 1.f);
        float r1 = __builtin_amdgcn_rcpf(q1 + 1.f);
        ea0 = fmaf(vv, fmaf(-2.f, r0, 1.f), ea0);
        ea1 = fmaf(vv, fmaf(-2.f, r1, 1.f), ea1);
    }
    float e0 = ea0 + pA[0];
    float e1 = ea1 + pA[1];

    // ---- block softmax over T=2048 ----
    float m = fmaxf(e0, e1);
    #pragma unroll
    for (int off = 32; off; off >>= 1) m = fmaxf(m, __shfl_xor(m, off));
    if (lane == 0) red[wid] = m;
    __syncthreads();
    if (wid == 0) {
        float mm = (lane < 16) ? red[lane] : -3.4e38f;
        #pragma unroll
        for (int off = 8; off; off >>= 1) mm = fmaxf(mm, __shfl_xor(mm, off));
        if (lane == 0) bc[0] = mm;
    }
    __syncthreads();
    const float M = bc[0];
    float x0 = __expf(e0 - M);
    float x1 = __expf(e1 - M);
    float s = x0 + x1;
    #pragma unroll
    for (int off = 32; off; off >>= 1) s += __shfl_xor(s, off);
    if (lane == 0) red[wid] = s;
    __syncthreads();
    if (wid == 0) {
        float ss = (lane < 16) ? red[lane] : 0.f;
        #pragma unroll
        for (int off = 8; off; off >>= 1) ss += __shfl_xor(ss, off);
        if (lane == 0) bc[1] = ss;
    }
    __syncthreads();
    const float inv = 1.f / bc[1];
    out[b * Tn + tid]        = x0 * inv;
    out[b * Tn + tid + 1024] = x1 * inv;
}

// ---------------------------------------------------------------------------
extern "C" void kernel_launch(void* const* d_in, const int* in_sizes, int n_in,
                              void* d_out, int out_size, void* d_ws, size_t ws_size,
                              hipStream_t stream) {
    const float* query = (const float*)d_in[0];
    const float* align = (const float*)d_in[1];
    const float* P     = (const float*)d_in[2];
    const float* W_w   = (const float*)d_in[3];
    const float* W_b   = (const float*)d_in[4];
    const float* V_w   = (const float*)d_in[5];
    const float* F_w   = (const float*)d_in[6];
    const float* U_w   = (const float*)d_in[7];
    const float* T_w   = (const float*)d_in[8];
    const float* T_b   = (const float*)d_in[9];
    const float* v_w   = (const float*)d_in[10];
    float* out  = (float*)d_out;
    float* G_ws = (float*)d_ws;   // 256*168 floats = 172 KB scratch

    g_kernel<<<Bsz, 256, 0, stream>>>(query, W_w, W_b, V_w, G_ws);
    e_kernel<<<Bsz, 1024, 0, stream>>>(align, P, F_w, U_w, T_w, T_b, v_w, G_ws, out);
}